// Round 4
// baseline (2932.035 us; speedup 1.0000x reference)
//
#include <hip/hip_runtime.h>
#include <hip/hip_cooperative_groups.h>

namespace cg = cooperative_groups;

#define NTRAIN 1024
#define NY 2
#define DDIM 128
#define NB 256
#define NITER 16
#define TT 1026          // NTRAIN + NY
#define TP 1088          // padded to 64-multiple (17*64)
#define SCALE_C 0.25f
#define GAMMA_C 0.05f
#define TAU_C 256.0f     // 2*D
#define KS2 68           // persistent kernel: k-span and n-span (16x16 grid decomposition)

__device__ __forceinline__ float sigm(float x) {
    return 1.0f / (1.0f + __expf(-x));
}

// ---------------- prep: p, base_logit, xsq, labels ----------------
__global__ void k_prep(const float* __restrict__ Xtr, const float* __restrict__ Xdef,
                       const float* __restrict__ worder, const float* __restrict__ wbase,
                       const int* __restrict__ ytr,
                       float* __restrict__ p, float* __restrict__ bl,
                       float* __restrict__ xsq, int* __restrict__ lbl) {
    int t = blockIdx.x;        // 0..TP-1
    int tx = threadIdx.x;      // 128 threads
    __shared__ float sp[128], sb[128], ss[128];
    float po = 0.f, bo = 0.f, sq = 0.f;
    if (t < TT) {
        const float* row = (t < NTRAIN) ? (Xtr + (size_t)t * DDIM)
                                        : (Xdef + (size_t)(t - NTRAIN) * DDIM);
        float x = row[tx];
        po = x * worder[tx];
        bo = x * wbase[tx];
        sq = x * x;
    }
    sp[tx] = po; sb[tx] = bo; ss[tx] = sq;
    __syncthreads();
    for (int off = 64; off > 0; off >>= 1) {
        if (tx < off) { sp[tx] += sp[tx+off]; sb[tx] += sb[tx+off]; ss[tx] += ss[tx+off]; }
        __syncthreads();
    }
    if (tx == 0) {
        p[t] = sp[0]; bl[t] = sb[0]; xsq[t] = ss[0];
        lbl[t] = (t < NTRAIN) ? ytr[t] : ((t < TT) ? (t - NTRAIN) : -1);
    }
}

// ---------------- Es[i,j] (default rows + pad zeroed) ----------------
__global__ void k_es(const float* __restrict__ p, float* __restrict__ Es) {
    int j = blockIdx.x * blockDim.x + threadIdx.x;
    int i = blockIdx.y;
    if (j >= TP) return;
    float v = 0.f;
    if (i < NTRAIN && j < TT) {   // is_default rows (i>=NTRAIN) and pads -> 0
        float x = SCALE_C * (p[i] - p[j]);
        float a = sigm(x);
        float b = sigm(-x);
        v = a * (1.f - b);
    }
    Es[(size_t)i * TP + j] = v;
}

// ---------------- partial blocked product (split-K over blockIdx.z) ----------------
// round-2 proven config: KC=16, kk-fast staging (moderate write conflicts, coalesced reads)
#define BT 64
#define KC 16
__global__ __launch_bounds__(256) void k_pblk(const float* __restrict__ Es,
                                              const int* __restrict__ lbl,
                                              float* __restrict__ P, int kspan) {
    __shared__ float Wt[KC][BT + 4];   // Wt[kk][ii] = Wm[i0+ii][k0+kk]
    __shared__ float Et[KC][BT + 4];   // Et[kk][jj] = Es[k0+kk][j0+jj]
    int i0 = blockIdx.y * BT, j0 = blockIdx.x * BT;
    int ks = blockIdx.z * kspan, ke = ks + kspan;
    int tid = threadIdx.x;
    int tx = tid & 15, ty = tid >> 4;
    float prod[4][4];
    #pragma unroll
    for (int a = 0; a < 4; a++)
        #pragma unroll
        for (int b = 0; b < 4; b++) prod[a][b] = 1.f;

    for (int k0 = ks; k0 < ke; k0 += KC) {
        __syncthreads();
        #pragma unroll
        for (int e = tid; e < KC * BT; e += 256) {   // Wt: kk fast -> coalesced global reads
            int kk = e & 15, ii = e >> 4;
            int gi = i0 + ii, gk = k0 + kk;
            float w = Es[(size_t)gi * TP + gk];
            if (lbl[gi] != lbl[gk] || gi == gk) w = 0.f;   // Wm: same-label, no diag
            Wt[kk][ii] = w;
        }
        #pragma unroll
        for (int e = tid; e < KC * BT; e += 256) {   // Et: jj fast -> coalesced
            int jj = e & 63, kk = e >> 6;
            Et[kk][jj] = Es[(size_t)(k0 + kk) * TP + j0 + jj];
        }
        __syncthreads();
        #pragma unroll
        for (int kk = 0; kk < KC; kk++) {
            float4 wv = *(const float4*)&Wt[kk][ty * 4];
            float4 ev = *(const float4*)&Et[kk][tx * 4];
            float w[4] = {wv.x, wv.y, wv.z, wv.w};
            float e[4] = {ev.x, ev.y, ev.z, ev.w};
            #pragma unroll
            for (int a = 0; a < 4; a++)
                #pragma unroll
                for (int b = 0; b < 4; b++)
                    prod[a][b] *= fmaf(-w[a], e[b], 1.f);
        }
    }
    float* Pz = P + (size_t)blockIdx.z * TP * TP;
    #pragma unroll
    for (int a = 0; a < 4; a++) {
        int i = i0 + ty * 4 + a;
        *(float4*)&Pz[(size_t)i * TP + j0 + tx * 4] =
            make_float4(prod[a][0], prod[a][1], prod[a][2], prod[a][3]);
    }
}

// ---------------- combine partials + assemble A ----------------
__global__ void k_afin(const float* __restrict__ P, int splits,
                       const float* __restrict__ Es, const float* __restrict__ p,
                       const int* __restrict__ lbl, float* __restrict__ A) {
    size_t idx = (size_t)blockIdx.x * 256 + threadIdx.x;
    if (idx >= (size_t)TP * TP) return;
    int i = (int)(idx / TP), j = (int)(idx % TP);
    float prod = P[idx];
    for (int r = 1; r < splits; r++) prod *= P[(size_t)r * TP * TP + idx];
    float v = 0.f;
    if (i < TT && j < TT) {
        int li = lbl[i], lj = lbl[j];
        bool same = (li == lj);
        float es = Es[idx];
        float att = same ? 0.f : es;
        float x = SCALE_C * (p[i] - p[j]);
        float sym = (!same && i < NTRAIN) ? sigm(x) * sigm(-x) : 0.f;
        v = -(att * prod + sym);
    }
    A[idx] = v;
}

// ---------------- qsq[m] = sum_d Xq[m][d]^2 ----------------
__global__ void k_qsq(const float* __restrict__ Xq, float* __restrict__ qsq) {
    int m = threadIdx.x;   // 256 threads, 1 block
    const float4* q4 = (const float4*)(Xq + (size_t)m * DDIM);
    float s = 0.f;
    #pragma unroll
    for (int d = 0; d < DDIM / 4; d++) {
        float4 q = q4[d];
        s = fmaf(q.x, q.x, fmaf(q.y, q.y, fmaf(q.z, q.z, fmaf(q.w, q.w, s))));
    }
    qsq[m] = s;
}

// ---------------- CT[t][m] = bl[t] - r(m,t);  ST[t][m] = sigm(bl[t]) ----------------
// transposed layout [TP][NB] so the persistent kernel's reads/writes are coalesced.
__global__ void k_cqT(const float* __restrict__ Xtr, const float* __restrict__ Xdef,
                      const float* __restrict__ Xq, const float* __restrict__ bl,
                      const float* __restrict__ xsq, const float* __restrict__ qsq,
                      float* __restrict__ CT, float* __restrict__ ST) {
    int t = blockIdx.x;      // 0..TP-1
    int m = threadIdx.x;     // 256 threads = query index
    __shared__ float xrow[DDIM];
    if (m < DDIM) {
        float x = 0.f;
        if (t < NTRAIN) x = Xtr[(size_t)t * DDIM + m];
        else if (t < TT) x = Xdef[(size_t)(t - NTRAIN) * DDIM + m];
        xrow[m] = x;
    }
    __syncthreads();
    float cv = 0.f, sv = 0.f;
    if (t < TT) {
        const float4* q4 = (const float4*)(Xq + (size_t)m * DDIM);
        const float4* x4 = (const float4*)xrow;
        float dot = 0.f;
        #pragma unroll
        for (int d = 0; d < DDIM / 4; d++) {
            float4 q = q4[d], x = x4[d];
            dot = fmaf(q.x, x.x, fmaf(q.y, x.y, fmaf(q.z, x.z, fmaf(q.w, x.w, dot))));
        }
        float sq = qsq[m] + xsq[t] - 2.f * dot;
        float r = sigm(GAMMA_C * (sq - TAU_C));
        cv = bl[t] - r;
        sv = sigm(bl[t]);
    }
    CT[(size_t)t * NB + m] = cv;   // pads -> 0 (never read anyway)
    ST[(size_t)t * NB + m] = sv;   // pad rows 0 -> padded k-loop exact
}

// ---------------- persistent cooperative kernel: all 16 iterations ----------------
// grid = 256 blocks (1/CU), block (kt,jt) owns A[kt*68:+68][jt*68:+68] in LDS for the
// whole kernel. Per iteration: phase A computes split-K partials (broadcast-FMA form),
// grid sync, phase B combines + sigmoid + writes ST (and final output on last iter).
__global__ __launch_bounds__(256) void k_persist(const float* __restrict__ Amat,
                                                 const float* __restrict__ CT,
                                                 float* __restrict__ ST,
                                                 float* __restrict__ PT,
                                                 float* __restrict__ out) {
    __shared__ float Al[KS2][KS2];   // 68*68*4 = 18496 B
    int bid = blockIdx.x;
    int kt = bid >> 4, jt = bid & 15;
    int k0 = kt * KS2, n0 = jt * KS2;
    int m = threadIdx.x;

    // stage A tile once: nn fast -> coalesced global reads, stride-1 LDS writes
    for (int e = m; e < KS2 * KS2; e += 256) {
        int nn = e % KS2, kk = e / KS2;
        Al[kk][nn] = Amat[(size_t)(k0 + kk) * TP + n0 + nn];
    }
    __syncthreads();

    cg::grid_group grid = cg::this_grid();
    float* pt = PT + (size_t)kt * TP * NB;

    for (int it = 0; it < NITER; it++) {
        // ---- phase A: acc[nn] = sum_kk ST[k0+kk][m] * Al[kk][nn] ----
        float acc[KS2];
        #pragma unroll
        for (int nn = 0; nn < KS2; nn++) acc[nn] = 0.f;
        #pragma unroll 4
        for (int kk = 0; kk < KS2; kk++) {
            float s = ST[(size_t)(k0 + kk) * NB + m];          // coalesced, L2-resident
            const float4* arow = (const float4*)&Al[kk][0];    // uniform addr -> broadcast
            #pragma unroll
            for (int nt = 0; nt < KS2 / 4; nt++) {
                float4 a4 = arow[nt];
                acc[nt * 4 + 0] = fmaf(s, a4.x, acc[nt * 4 + 0]);
                acc[nt * 4 + 1] = fmaf(s, a4.y, acc[nt * 4 + 1]);
                acc[nt * 4 + 2] = fmaf(s, a4.z, acc[nt * 4 + 2]);
                acc[nt * 4 + 3] = fmaf(s, a4.w, acc[nt * 4 + 3]);
            }
        }
        #pragma unroll
        for (int nn = 0; nn < KS2; nn++)
            pt[(size_t)(n0 + nn) * NB + m] = acc[nn];          // coalesced 1KB stores
        __threadfence();
        grid.sync();

        // ---- phase B: combine 16 partials + c, sigmoid, write ST ----
        int gbase = bid * TP;   // TP elements per block covers TP*NB total
        for (int e = m; e < TP; e += 256) {
            int g = gbase + e;
            int t = g >> 8, mm = g & 255;
            if (t < TT) {
                float sum = CT[(size_t)t * NB + mm];
                #pragma unroll
                for (int z = 0; z < 16; z++)
                    sum += PT[(size_t)z * TP * NB + (size_t)t * NB + mm];
                float v = sigm(sum);
                ST[(size_t)t * NB + mm] = v;
                if (it == NITER - 1 && t >= NTRAIN)
                    out[mm * NY + (t - NTRAIN)] = v;
            }
        }
        __threadfence();
        grid.sync();
    }
}

extern "C" void kernel_launch(void* const* d_in, const int* in_sizes, int n_in,
                              void* d_out, int out_size, void* d_ws, size_t ws_size,
                              hipStream_t stream) {
    const float* Xtr    = (const float*)d_in[0];
    const float* Xdef   = (const float*)d_in[1];
    const float* Xq     = (const float*)d_in[2];
    const float* worder = (const float*)d_in[3];
    const float* wbase  = (const float*)d_in[4];
    const int*   ytr    = (const int*)d_in[5];

    const size_t MAT = (size_t)TP * TP * 4;        // 4.73 MB
    const size_t VEC = (size_t)TP * NB * 4;        // 1.11 MB
    const size_t SMALL = 5 * 4608;
    const size_t PTB = (size_t)16 * VEC;           // 17.8 MB partial buffer
    auto need = [&](int s) {
        size_t preg = (size_t)s * MAT;
        if (preg < PTB) preg = PTB;
        return SMALL + 2 * MAT + preg + 2 * VEC + 8192;
    };
    int splits = 4;
    if (ws_size < need(4)) splits = 2;

    char* ws = (char*)d_ws;
    size_t off = 0;
    auto alloc = [&](size_t bytes) {
        void* r = ws + off;
        off += (bytes + 255) & ~(size_t)255;
        return r;
    };
    float* p    = (float*)alloc((size_t)TP * 4);
    float* bl   = (float*)alloc((size_t)TP * 4);
    float* xsq  = (float*)alloc((size_t)TP * 4);
    int*   lbl  = (int*)  alloc((size_t)TP * 4);
    float* qsq  = (float*)alloc((size_t)NB * 4);
    float* Es   = (float*)alloc(MAT);
    float* Amat = (float*)alloc(MAT);
    size_t preg = (size_t)splits * MAT;
    if (preg < PTB) preg = PTB;
    float* P    = (float*)alloc(preg);     // k_pblk partials, then k_persist PT
    float* CT   = (float*)alloc(VEC);
    float* ST   = (float*)alloc(VEC);

    int kspan = TP / splits;

    k_prep<<<TP, 128, 0, stream>>>(Xtr, Xdef, worder, wbase, ytr, p, bl, xsq, lbl);
    k_es<<<dim3((TP + 255) / 256, TP), 256, 0, stream>>>(p, Es);
    k_pblk<<<dim3(TP / BT, TP / BT, splits), 256, 0, stream>>>(Es, lbl, P, kspan);
    k_afin<<<(int)(((size_t)TP * TP + 255) / 256), 256, 0, stream>>>(P, splits, Es, p, lbl, Amat);
    k_qsq<<<1, 256, 0, stream>>>(Xq, qsq);
    k_cqT<<<TP, 256, 0, stream>>>(Xtr, Xdef, Xq, bl, xsq, qsq, CT, ST);

    float* outp = (float*)d_out;
    void* kargs[] = { (void*)&Amat, (void*)&CT, (void*)&ST, (void*)&P, (void*)&outp };
    hipLaunchCooperativeKernel((void*)k_persist, dim3(256), dim3(256), kargs, 0, stream);
}

// Round 5
// 471.682 us; speedup vs baseline: 6.2161x; 6.2161x over previous
//
#include <hip/hip_runtime.h>

#define NTRAIN 1024
#define NY 2
#define DDIM 128
#define NB 256
#define NITER 16
#define TT 1026          // NTRAIN + NY
#define TP 1088          // orig-index padding (for p/bl/xsq arrays)
#define CP 640           // class panel size (10*64); holds up to 639 train + 1 default
#define TPP (2*CP)       // 1280 permuted slots
#define SCALE_C 0.25f
#define GAMMA_C 0.05f
#define TAU_C 256.0f     // 2*D
#define ISPLIT 8         // split-K for iteration GEMM (kspan 80 within opposite panel)
#define IKS (CP/ISPLIT)  // 80

__device__ __forceinline__ float sigm(float x) {
    return 1.0f / (1.0f + __expf(-x));
}

// ---------------- prep: p, base_logit, xsq (orig index space) ----------------
__global__ void k_prep(const float* __restrict__ Xtr, const float* __restrict__ Xdef,
                       const float* __restrict__ worder, const float* __restrict__ wbase,
                       float* __restrict__ p, float* __restrict__ bl,
                       float* __restrict__ xsq) {
    int t = blockIdx.x;        // 0..TP-1
    int tx = threadIdx.x;      // 128 threads
    __shared__ float sp[128], sb[128], ss[128];
    float po = 0.f, bo = 0.f, sq = 0.f;
    if (t < TT) {
        const float* row = (t < NTRAIN) ? (Xtr + (size_t)t * DDIM)
                                        : (Xdef + (size_t)(t - NTRAIN) * DDIM);
        float x = row[tx];
        po = x * worder[tx];
        bo = x * wbase[tx];
        sq = x * x;
    }
    sp[tx] = po; sb[tx] = bo; ss[tx] = sq;
    __syncthreads();
    for (int off = 64; off > 0; off >>= 1) {
        if (tx < off) { sp[tx] += sp[tx+off]; sb[tx] += sb[tx+off]; ss[tx] += ss[tx+off]; }
        __syncthreads();
    }
    if (tx == 0) { p[t] = sp[0]; bl[t] = sb[0]; xsq[t] = ss[0]; }
}

// ---------------- label-sort permutation: map[slot] -> orig index (-1 = pad) ----------------
// panel c = [c*CP, (c+1)*CP); train members by rank, default c at slot c*CP+CP-1.
__global__ void k_perm(const int* __restrict__ ytr, const float* __restrict__ p,
                       int* __restrict__ map, float* __restrict__ pp) {
    __shared__ int ly[NTRAIN];
    int tid = threadIdx.x;                 // 1024 threads
    ly[tid] = ytr[tid];
    for (int a = tid; a < TPP; a += 1024) map[a] = -1;
    __syncthreads();
    int c = ly[tid];
    int rank = 0;
    for (int j = 0; j < NTRAIN; j++) {     // uniform loop, LDS broadcast
        int v = ly[j];
        if (j < tid && v == c) rank++;
    }
    if (rank < CP - 1) map[c * CP + rank] = tid;
    if (tid < NY) map[tid * CP + CP - 1] = NTRAIN + tid;
    __syncthreads();
    for (int a = tid; a < TPP; a += 1024) {
        int m = map[a];
        pp[a] = (m >= 0) ? p[m] : 0.f;
    }
}

// ---------------- Es'[a,b] = sigma(0.25(p_a-p_b))^2 in permuted space ----------------
// (1 - E^T = E, so Es = E*E; default rows and pads -> 0)
__global__ void k_es2(const int* __restrict__ map, const float* __restrict__ pp,
                      float* __restrict__ Es) {
    int b = blockIdx.x * 256 + threadIdx.x;   // col slot (TPP = 5*256)
    int a = blockIdx.y;                       // row slot
    float v = 0.f;
    int mi = map[a], mj = map[b];
    if (mi >= 0 && mi < NTRAIN && mj >= 0) {
        float e = sigm(SCALE_C * (pp[a] - pp[b]));
        v = e * e;
    }
    Es[(size_t)a * TPP + b] = v;
}

// ---------------- partial blocked product, cross-panel only ----------------
// blockIdx.z = slab: c = z&1 (i-panel), kz = z>>1 (k-split within panel c).
// i in panel c, j in panel 1-c, k over panel c slice. Wm mask: same-panel (auto) minus diag.
#define KC 16
__global__ __launch_bounds__(256) void k_pblk2(const float* __restrict__ Es,
                                               float* __restrict__ P, int kspan) {
    __shared__ float Wt[KC][64 + 4];
    __shared__ float Et[KC][64 + 4];
    int c  = blockIdx.z & 1;
    int kz = blockIdx.z >> 1;
    int i0 = c * CP + blockIdx.y * 64;
    int j0 = (1 - c) * CP + blockIdx.x * 64;
    int ks = c * CP + kz * kspan, ke = ks + kspan;
    int tid = threadIdx.x;
    int tx = tid & 15, ty = tid >> 4;
    float prod[4][4];
    #pragma unroll
    for (int a = 0; a < 4; a++)
        #pragma unroll
        for (int b = 0; b < 4; b++) prod[a][b] = 1.f;

    for (int k0 = ks; k0 < ke; k0 += KC) {
        __syncthreads();
        #pragma unroll
        for (int e = tid; e < KC * 64; e += 256) {   // Wt: kk fast
            int kk = e & 15, ii = e >> 4;
            int gi = i0 + ii, gk = k0 + kk;
            float w = Es[(size_t)gi * TPP + gk];     // same-panel: same-label by construction
            if (gi == gk) w = 0.f;                   // no diag
            Wt[kk][ii] = w;
        }
        #pragma unroll
        for (int e = tid; e < KC * 64; e += 256) {   // Et: jj fast -> coalesced
            int jj = e & 63, kk = e >> 6;
            Et[kk][jj] = Es[(size_t)(k0 + kk) * TPP + j0 + jj];
        }
        __syncthreads();
        #pragma unroll
        for (int kk = 0; kk < KC; kk++) {
            float4 wv = *(const float4*)&Wt[kk][ty * 4];
            float4 ev = *(const float4*)&Et[kk][tx * 4];
            float w[4] = {wv.x, wv.y, wv.z, wv.w};
            float e[4] = {ev.x, ev.y, ev.z, ev.w};
            #pragma unroll
            for (int a = 0; a < 4; a++)
                #pragma unroll
                for (int b = 0; b < 4; b++)
                    prod[a][b] *= fmaf(-w[a], e[b], 1.f);
        }
    }
    // P slab layout: [slab = kz*2+c == blockIdx.z][iil 640][jjl 640]
    float* Pz = P + (size_t)blockIdx.z * CP * CP;
    int jjl = blockIdx.x * 64 + tx * 4;
    #pragma unroll
    for (int a = 0; a < 4; a++) {
        int iil = blockIdx.y * 64 + ty * 4 + a;
        *(float4*)&Pz[(size_t)iil * CP + jjl] =
            make_float4(prod[a][0], prod[a][1], prod[a][2], prod[a][3]);
    }
}

// ---------------- combine partials + assemble A' (cross blocks only) ----------------
__global__ void k_afin2(const float* __restrict__ P, int psplit,
                        const int* __restrict__ map, const float* __restrict__ pp,
                        const float* __restrict__ Es, float* __restrict__ A) {
    size_t e = (size_t)blockIdx.x * 256 + threadIdx.x;   // 2*CP*CP threads
    int c = (int)(e / ((size_t)CP * CP));
    int rem = (int)(e % ((size_t)CP * CP));
    int iil = rem / CP, jjl = rem % CP;
    int a = c * CP + iil, b = (1 - c) * CP + jjl;
    float prod = P[(size_t)c * CP * CP + rem];
    for (int kz = 1; kz < psplit; kz++)
        prod *= P[(size_t)(kz * 2 + c) * CP * CP + rem];
    float v = 0.f;
    int mi = map[a], mj = map[b];
    if (mi >= 0 && mj >= 0) {
        float es = Es[(size_t)a * TPP + b];              // attacks (cross-panel => diff labels)
        float x = SCALE_C * (pp[a] - pp[b]);
        float E = sigm(x);
        float sym = (mi < NTRAIN) ? E * (1.f - E) : 0.f; // E * E^T, default rows masked
        v = -(es * prod + sym);
    }
    A[(size_t)a * TPP + b] = v;
}

// ---------------- CT[b][t] = bl - r, S0 = sigma(bl), permuted, row-major [NB][TPP] ----------------
__global__ void k_cq2(const float* __restrict__ Xtr, const float* __restrict__ Xdef,
                      const float* __restrict__ Xq, const float* __restrict__ bl,
                      const int* __restrict__ map,
                      float* __restrict__ CT, float* __restrict__ S0) {
    int bq = blockIdx.y;
    int t = blockIdx.x * 256 + threadIdx.x;
    int mi = map[t];
    float cv = 0.f, sv = 0.f;
    if (mi >= 0) {
        const float4* q4 = (const float4*)(Xq + (size_t)bq * DDIM);
        const float* row = (mi < NTRAIN) ? (Xtr + (size_t)mi * DDIM)
                                         : (Xdef + (size_t)(mi - NTRAIN) * DDIM);
        const float4* x4 = (const float4*)row;
        float dot = 0.f, qs = 0.f, xs = 0.f;
        #pragma unroll
        for (int d = 0; d < DDIM / 4; d++) {
            float4 q = q4[d], x = x4[d];
            dot = fmaf(q.x, x.x, fmaf(q.y, x.y, fmaf(q.z, x.z, fmaf(q.w, x.w, dot))));
            qs  = fmaf(q.x, q.x, fmaf(q.y, q.y, fmaf(q.z, q.z, fmaf(q.w, q.w, qs))));
            xs  = fmaf(x.x, x.x, fmaf(x.y, x.y, fmaf(x.z, x.z, fmaf(x.w, x.w, xs))));
        }
        float sq = qs + xs - 2.f * dot;
        float r = sigm(GAMMA_C * (sq - TAU_C));
        cv = bl[mi] - r;
        sv = sigm(bl[mi]);
    }
    CT[(size_t)bq * TPP + t] = cv;
    S0[(size_t)bq * TPP + t] = sv;
}

// ---------------- iteration partial: PT[z] = S[:, kslab(opposite panel)] @ A'[kslab, jtile] ----------------
// grid (20 j-tiles, 4 b-tiles, ISPLIT); K per column = 640 (A' block-antidiagonal).
__global__ __launch_bounds__(256) void k_ipart2(const float* __restrict__ S,
                                                const float* __restrict__ A,
                                                float* __restrict__ PT) {
    __shared__ float St[IKS][68];   // St[kk][bb]; row stride 272B (16B-aligned)
    __shared__ float At[IKS][68];   // At[kk][jj]
    int jt = blockIdx.x;
    int b0 = blockIdx.y * 64;
    int z  = blockIdx.z;
    int d  = (jt >= CP / 64) ? 1 : 0;        // panel of output columns
    int j0 = jt * 64;
    int k0 = (1 - d) * CP + z * IKS;         // k-slab in OPPOSITE panel
    int tid = threadIdx.x;
    int tx = tid & 15, ty = tid >> 4;

    for (int e = tid; e < 64 * IKS; e += 256) {      // kk fast -> coalesced
        int kk = e % IKS, bb = e / IKS;
        St[kk][bb] = S[(size_t)(b0 + bb) * TPP + k0 + kk];
    }
    for (int e = tid; e < 64 * IKS; e += 256) {      // jj fast -> coalesced
        int jj = e & 63, kk = e >> 6;
        At[kk][jj] = A[(size_t)(k0 + kk) * TPP + j0 + jj];
    }
    __syncthreads();

    float acc[4][4];
    #pragma unroll
    for (int a = 0; a < 4; a++)
        #pragma unroll
        for (int b = 0; b < 4; b++) acc[a][b] = 0.f;

    #pragma unroll 4
    for (int kk = 0; kk < IKS; kk++) {
        float4 sv = *(const float4*)&St[kk][ty * 4];
        float4 av = *(const float4*)&At[kk][tx * 4];
        float s[4] = {sv.x, sv.y, sv.z, sv.w};
        float a4[4] = {av.x, av.y, av.z, av.w};
        #pragma unroll
        for (int a = 0; a < 4; a++)
            #pragma unroll
            for (int b = 0; b < 4; b++)
                acc[a][b] = fmaf(s[a], a4[b], acc[a][b]);
    }

    float* Pz = PT + (size_t)z * NB * TPP;
    #pragma unroll
    for (int a = 0; a < 4; a++) {
        int b = b0 + ty * 4 + a;
        *(float4*)&Pz[(size_t)b * TPP + j0 + tx * 4] =
            make_float4(acc[a][0], acc[a][1], acc[a][2], acc[a][3]);
    }
}

// ---------------- combine split-K partials + sigmoid ----------------
__global__ void k_comb2(const float* __restrict__ PT, const float* __restrict__ CT,
                        const int* __restrict__ map, float* __restrict__ Snew) {
    size_t idx = (size_t)blockIdx.x * 256 + threadIdx.x;   // NB*TPP = 1280*256
    int n = (int)(idx % TPP);
    float sum = CT[idx];
    #pragma unroll
    for (int z = 0; z < ISPLIT; z++) sum += PT[(size_t)z * NB * TPP + idx];
    Snew[idx] = (map[n] >= 0) ? sigm(sum) : 0.f;
}

// ---------------- extract default slots ----------------
__global__ void k_out2(const float* __restrict__ S, float* __restrict__ out) {
    int idx = threadIdx.x;
    if (idx < NB * NY) {
        int m = idx >> 1, c = idx & 1;
        out[idx] = S[(size_t)m * TPP + c * CP + CP - 1];
    }
}

extern "C" void kernel_launch(void* const* d_in, const int* in_sizes, int n_in,
                              void* d_out, int out_size, void* d_ws, size_t ws_size,
                              hipStream_t stream) {
    const float* Xtr    = (const float*)d_in[0];
    const float* Xdef   = (const float*)d_in[1];
    const float* Xq     = (const float*)d_in[2];
    const float* worder = (const float*)d_in[3];
    const float* wbase  = (const float*)d_in[4];
    const int*   ytr    = (const int*)d_in[5];

    const size_t MATP = (size_t)TPP * TPP * 4;     // 6.55 MB
    const size_t VECP = (size_t)NB * TPP * 4;      // 1.31 MB
    const size_t PTB  = (size_t)ISPLIT * VECP;     // 10.49 MB
    auto need = [&](int ps) {
        size_t pr = (size_t)ps * 2 * CP * CP * 4;
        if (pr < PTB) pr = PTB;
        return (size_t)(8 * 8192) + 2 * MATP + pr + 3 * VECP + 65536;
    };
    int psplit = 4;
    if (ws_size < need(4)) psplit = 2;
    int kspan = CP / psplit;                        // 160 or 320 (multiple of KC)

    char* ws = (char*)d_ws;
    size_t off = 0;
    auto alloc = [&](size_t bytes) {
        void* r = ws + off;
        off += (bytes + 255) & ~(size_t)255;
        return r;
    };
    float* p    = (float*)alloc((size_t)TP * 4);
    float* bl   = (float*)alloc((size_t)TP * 4);
    float* xsq  = (float*)alloc((size_t)TP * 4);
    int*   map  = (int*)  alloc((size_t)TPP * 4);
    float* pp   = (float*)alloc((size_t)TPP * 4);
    float* Es   = (float*)alloc(MATP);
    float* Amat = (float*)alloc(MATP);
    size_t preg = (size_t)psplit * 2 * CP * CP * 4;
    if (preg < PTB) preg = PTB;
    float* P    = (float*)alloc(preg);             // pblk partials, then iter partials
    float* CT   = (float*)alloc(VECP);
    float* s0   = (float*)alloc(VECP);
    float* s1   = (float*)alloc(VECP);

    k_prep<<<TP, 128, 0, stream>>>(Xtr, Xdef, worder, wbase, p, bl, xsq);
    k_perm<<<1, 1024, 0, stream>>>(ytr, p, map, pp);
    k_es2<<<dim3(TPP / 256, TPP), 256, 0, stream>>>(map, pp, Es);
    k_pblk2<<<dim3(CP / 64, CP / 64, 2 * psplit), 256, 0, stream>>>(Es, P, kspan);
    k_afin2<<<(int)((2 * (size_t)CP * CP) / 256), 256, 0, stream>>>(P, psplit, map, pp, Es, Amat);
    k_cq2<<<dim3(TPP / 256, NB), 256, 0, stream>>>(Xtr, Xdef, Xq, bl, map, CT, s0);

    float* cur = s0;
    float* nxt = s1;
    const int nvec = (int)(((size_t)NB * TPP) / 256);
    for (int it = 0; it < NITER; it++) {
        k_ipart2<<<dim3(TPP / 64, NB / 64, ISPLIT), 256, 0, stream>>>(cur, Amat, P);
        k_comb2<<<nvec, 256, 0, stream>>>(P, CT, map, nxt);
        float* t = cur; cur = nxt; nxt = t;
    }
    k_out2<<<1, 512, 0, stream>>>(cur, (float*)d_out);
}